// Round 10
// baseline (99.528 us; speedup 1.0000x reference)
//
#include <hip/hip_runtime.h>
#include <hip/hip_bf16.h>

#define H_DIM   64
#define T_STEPS 128
#define B_TOT   4096
#define BB      8     // batch rows per block; 512 blocks -> 2 independent blocks/CU
#define SK      72    // padded row stride in halves for sX/sH
#define NTHREADS 256  // 4 waves; wave w owns h-cols w*16..w*16+15, all 4 gates
#define XBATCH  8     // x prefetch depth; must divide T_STEPS

typedef _Float16 half8  __attribute__((ext_vector_type(8)));
typedef __fp16   fp16x2 __attribute__((ext_vector_type(2)));
typedef __attribute__((ext_vector_type(4))) float f32x4;

#if __has_builtin(__builtin_amdgcn_exp2f)
#define EXP2(x) __builtin_amdgcn_exp2f(x)
#else
#define EXP2(x) exp2f(x)
#endif

// Weights/biases pre-scaled by log2(e) (i,f,o) or 2*log2(e) (g): activations
// are raw exp2-domain. c is kept in the 2*log2(e)-scaled domain so the c->h
// tanh needs no multiply on the critical tail.
__device__ __forceinline__ float sigmoid2(float xp) {      // xp = x*log2e
    return __builtin_amdgcn_rcpf(1.0f + EXP2(-xp));        // exact at +-inf
}
__device__ __forceinline__ float tanh2(float xp) {         // xp = 2*log2e*x
    return fmaf(-2.0f, __builtin_amdgcn_rcpf(EXP2(xp) + 1.0f), 1.0f);
}

// lane l <-> l^8 exchange within each 16-lane row: row_ror:8 DPP (VALU speed).
__device__ __forceinline__ float xor8_dpp(float v) {
    return __int_as_float(__builtin_amdgcn_mov_dpp(
        __float_as_int(v), 0x128 /*row_ror:8*/, 0xf, 0xf, false));
}

// A = [x (64) | h (64)] f16, K=128, M-tile=16 with the 8 batch rows placed at
// M-rows {0,1,4,5,8,9,12,13} (br -> m = (br>>1)*4 + (br&1)), so the valid
// accumulator slots are r in {0,1} for EVERY lk: all 64 lanes own exactly 2
// valid cell sites (cg=0,1 at row r* = losd?0:1). No idle lanes, no duplicated
// trans work, and 2 independent blocks/CU can slip phases to hide the chain.
// Packing per wave: 4 tiles (q: gate-pair i,f / g,o) x (cg: col-half);
// tile n=lrow -> gate q*2+(lrow>>3), col w*16+cg*8+(lrow&7).
__global__ __launch_bounds__(NTHREADS) void lstm_fused(
    const int* __restrict__ inst, const float* __restrict__ embed,
    const float* __restrict__ Wih, const float* __restrict__ Whh,
    const float* __restrict__ bih, const float* __restrict__ bhh,
    float* __restrict__ out)
{
    __shared__ __align__(16) _Float16 sX[2][16][SK];   // 4.6 KB x staging (f16)
    __shared__ __align__(16) _Float16 sH[2][16][SK];   // 4.6 KB h staging (f16)
    __shared__ int sInst[BB * T_STEPS];                // 4 KB

    const int tid  = (int)threadIdx.x;
    const int w    = tid >> 6;          // wave 0..3
    const int l    = tid & 63;
    const int lrow = l & 15;            // A-row (m) / packed-n for B & C/D
    const int lk   = l >> 4;            // k-block; C/D rows are lk*4 + 0..3
    const bool losd = (lrow < 8);       // low gate-half of the packed tile
    const int colbase = w * 16 + (lrow & 7);   // col of cg=0 site
    const int rstar = losd ? 0 : 1;     // this lane's valid accumulator slot
    const int mrow  = lk * 4 + rstar;   // M-row of this lane's sites
    const int br    = lk * 2 + rstar;   // batch row of this lane's sites
    const int b0    = (int)blockIdx.x * BB;

    const float L2E     = 1.4426950408889634f;
    const float TWO_L2E = 2.8853900817779268f;

    // stage this block's instruction indices (8 rows x 128 steps)
    for (int i = tid; i < BB * T_STEPS; i += NTHREADS)
        sInst[i] = inst[b0 * T_STEPS + i];

    // zero all staging once: covers h0=0 AND the 8 permanently-garbage M-rows
    for (int i = tid; i < 2 * 16 * SK; i += NTHREADS) {
        ((_Float16*)sX)[i] = (_Float16)0.0f;
        ((_Float16*)sH)[i] = (_Float16)0.0f;
    }
    __syncthreads();

    // weight B-fragments (f16, exp2-prescaled): wf[cg][q][kf]
    // kf 0,1 -> W_ih k 0..63 ; kf 2,3 -> W_hh k 0..63
    half8 wf[2][2][4];
    float bias[2][2];
#pragma unroll
    for (int cg = 0; cg < 2; ++cg) {
#pragma unroll
        for (int q = 0; q < 2; ++q) {
            const int gate = q * 2 + (lrow >> 3);
            const float ws = (gate == 2) ? TWO_L2E : L2E;  // g feeds tanh(2x form)
            const int gcol = gate * 64 + colbase + cg * 8; // W output row 0..255
            bias[cg][q] = (bih[gcol] + bhh[gcol]) * ws;
#pragma unroll
            for (int kf = 0; kf < 4; ++kf) {
                const float* src = (kf < 2 ? Wih : Whh) + (long)gcol * H_DIM + (kf & 1) * 32 + lk * 8;
                half8 v;
#pragma unroll
                for (int jj = 0; jj < 8; ++jj) v[jj] = (_Float16)(src[jj] * ws);
                wf[cg][q][kf] = v;
            }
        }
    }

    // x staging: 256 threads = 8 batch rows x 32 float2 chunks, exact cover.
    // Batch row xr lands at LDS/M-row xm = (xr>>1)*4 + (xr&1).
    const int xr = tid >> 5;       // 0..7
    const int xc = tid & 31;       // 0..31
    const int xm = (xr >> 1) * 4 + (xr & 1);
    {   // x(0) straight to LDS
        const int idx = sInst[xr * T_STEPS + 0];
        const float2 xv = *reinterpret_cast<const float2*>(embed + (long)idx * H_DIM + xc * 2);
        fp16x2 hp = __builtin_amdgcn_cvt_pkrtz(xv.x, xv.y);
        *reinterpret_cast<fp16x2*>(&sX[0][xm][xc * 2]) = hp;
    }

    // register x-buffer (static indices only): entry (tt-1)&7 holds x(tt)
    float2 xbuf[XBATCH];
#pragma unroll
    for (int j = 0; j < XBATCH; ++j) {
        const int idx = sInst[xr * T_STEPS + 1 + j];
        xbuf[j] = *reinterpret_cast<const float2*>(embed + (long)idx * H_DIM + xc * 2);
    }
    __syncthreads();

    // c (2L2E-scaled domain) and h for this lane's 2 sites (cg = 0,1)
    float creg[2] = {0.f, 0.f};
    float hreg[2] = {0.f, 0.f};

    for (int tb = 0; tb < T_STEPS; tb += XBATCH) {
#pragma unroll
        for (int j = 0; j < XBATCH; ++j) {
            const int t   = tb + j;
            const int buf = j & 1;          // tb multiple of 8 -> static parity
            const int ob  = buf ^ 1;
            const bool pf = (t + 1 < T_STEPS);

            const float2 xcur = xbuf[j];    // x for step t+1 (loaded >=1 step ago)

            // refill burst once per XBATCH steps: x(t+2 .. t+9)
            if (j == XBATCH - 1 && pf) {
#pragma unroll
                for (int jj = 0; jj < XBATCH; ++jj) {
                    const int tt = t + 2 + jj;
                    if (tt < T_STEPS) {
                        const int idx = sInst[xr * T_STEPS + tt];
                        xbuf[jj] = *reinterpret_cast<const float2*>(embed + (long)idx * H_DIM + xc * 2);
                    }
                }
            }

            // A-fragments (f16): lane (m=lrow, lk) reads 16B contiguous
            half8 a0 = *reinterpret_cast<const half8*>(&sX[buf][lrow][lk * 8]);
            half8 a1 = *reinterpret_cast<const half8*>(&sX[buf][lrow][32 + lk * 8]);
            half8 a2 = *reinterpret_cast<const half8*>(&sH[buf][lrow][lk * 8]);
            half8 a3 = *reinterpret_cast<const half8*>(&sH[buf][lrow][32 + lk * 8]);

            // 4 packed tiles, 4 independent 4-deep MFMA chains (ILP across tiles)
            f32x4 acc[2][2];
#pragma unroll
            for (int cg = 0; cg < 2; ++cg) {
#pragma unroll
                for (int q = 0; q < 2; ++q) {
                    f32x4 a = {bias[cg][q], bias[cg][q], bias[cg][q], bias[cg][q]};
                    a = __builtin_amdgcn_mfma_f32_16x16x32_f16(a0, wf[cg][q][0], a, 0, 0, 0);
                    a = __builtin_amdgcn_mfma_f32_16x16x32_f16(a1, wf[cg][q][1], a, 0, 0, 0);
                    a = __builtin_amdgcn_mfma_f32_16x16x32_f16(a2, wf[cg][q][2], a, 0, 0, 0);
                    a = __builtin_amdgcn_mfma_f32_16x16x32_f16(a3, wf[cg][q][3], a, 0, 0, 0);
                    acc[cg][q] = a;
                }
            }

            // per col-half: gate exchange (DPP xor8) + cell update at row r*
#pragma unroll
            for (int cg = 0; cg < 2; ++cg) {
                // local gate at own row; send partner's-row value, receive ours
                const float loc0 = losd ? acc[cg][0][0] : acc[cg][0][1];
                const float loc1 = losd ? acc[cg][1][0] : acc[cg][1][1];
                const float rem0 = xor8_dpp(losd ? acc[cg][0][1] : acc[cg][0][0]);
                const float rem1 = xor8_dpp(losd ? acc[cg][1][1] : acc[cg][1][0]);
                const float vi = losd ? loc0 : rem0;   // i lives in low gate-half
                const float vf = losd ? rem0 : loc0;
                const float vg = losd ? loc1 : rem1;   // g lives in low gate-half
                const float vo = losd ? rem1 : loc1;

                const float iv = sigmoid2(vi);
                const float fv = sigmoid2(vf);
                const float gv = tanh2(vg);
                const float ov = sigmoid2(vo);
                const float g2 = gv * TWO_L2E;          // keep c in scaled domain
                const float cs = fmaf(fv, creg[cg], iv * g2);
                creg[cg] = cs;
                hreg[cg] = ov * tanh2(cs);              // no mul on the tail

                if (pf)
                    sH[ob][mrow][colbase + cg * 8] = (_Float16)hreg[cg];
            }

            // publish prefetched x (f16, pkrtz) into next buffer
            if (pf) {
                fp16x2 hp = __builtin_amdgcn_cvt_pkrtz(xcur.x, xcur.y);
                *reinterpret_cast<fp16x2*>(&sX[ob][xm][xc * 2]) = hp;
            }
            __syncthreads();   // sX/sH[ob] visible before next step
        }
    }

    // final h (f32) -> out[B][H]; each lane owns (br, colbase) and (br, colbase+8)
    out[(long)(b0 + br) * H_DIM + colbase]     = hreg[0];
    out[(long)(b0 + br) * H_DIM + colbase + 8] = hreg[1];
}

extern "C" void kernel_launch(void* const* d_in, const int* in_sizes, int n_in,
                              void* d_out, int out_size, void* d_ws, size_t ws_size,
                              hipStream_t stream) {
    const int*   inst  = (const int*)  d_in[0];
    const float* embed = (const float*)d_in[1];
    const float* Wih   = (const float*)d_in[2];
    const float* Whh   = (const float*)d_in[3];
    const float* bih   = (const float*)d_in[4];
    const float* bhh   = (const float*)d_in[5];
    float* out = (float*)d_out;

    lstm_fused<<<B_TOT / BB, NTHREADS, 0, stream>>>(inst, embed, Wih, Whh, bih, bhh, out);
}

// Round 11
// 80.962 us; speedup vs baseline: 1.2293x; 1.2293x over previous
//
#include <hip/hip_runtime.h>
#include <hip/hip_bf16.h>

#define H_DIM   64
#define T_STEPS 128
#define B_TOT   4096
#define BB      8     // batch rows per block; 512 blocks -> 2 independent blocks/CU
#define SK      72    // padded row stride in halves for sX/sH
#define NTHREADS 512  // 8 waves; wave w owns cols w*8..w*8+7 (both gate halves)
#define XBATCH  8     // x prefetch depth; must divide T_STEPS

typedef _Float16 half8  __attribute__((ext_vector_type(8)));
typedef __attribute__((ext_vector_type(4))) float f32x4;

#if __has_builtin(__builtin_amdgcn_exp2f)
#define EXP2(x) __builtin_amdgcn_exp2f(x)
#else
#define EXP2(x) exp2f(x)
#endif

// Weights/biases pre-scaled by log2(e) (i,f,o) or 2*log2(e) (g): activations
// are raw exp2-domain. c lives in the 2*log2(e)-scaled domain so the c->h
// tanh needs no multiply on the critical tail.
__device__ __forceinline__ float sigmoid2(float xp) {      // xp = x*log2e
    return __builtin_amdgcn_rcpf(1.0f + EXP2(-xp));        // exact at +-inf
}
__device__ __forceinline__ float tanh2(float xp) {         // xp = 2*log2e*x
    return fmaf(-2.0f, __builtin_amdgcn_rcpf(EXP2(xp) + 1.0f), 1.0f);
}

// lane l <-> l^8 exchange within each 16-lane row: row_ror:8 DPP (VALU speed).
__device__ __forceinline__ float xor8_dpp(float v) {
    return __int_as_float(__builtin_amdgcn_mov_dpp(
        __float_as_int(v), 0x128 /*row_ror:8*/, 0xf, 0xf, false));
}

// A = [x (64) | h (64)] f16, K=128, M-tile=16 with the 8 batch rows placed at
// M-rows {0,1,4,5,8,9,12,13} (br -> m = (br>>1)*4 + (br&1)) so the valid
// accumulator slots are r in {0,1} for EVERY lk. ONE cell site per lane:
// xor8-partner lanes (same col, gate halves) split the two row-slots
// (losd takes r=0, hi takes r=1) -> 10 trans/lane/step, 2 DPP exchange ops.
// 8 waves/block, 2 independent blocks/CU -> 4 waves/SIMD from 2 barrier groups.
__global__ __launch_bounds__(NTHREADS, 4) void lstm_fused(
    const int* __restrict__ inst, const float* __restrict__ embed,
    const float* __restrict__ Wih, const float* __restrict__ Whh,
    const float* __restrict__ bih, const float* __restrict__ bhh,
    float* __restrict__ out)
{
    __shared__ __align__(16) _Float16 sX[2][16][SK];   // 4.6 KB x staging (f16)
    __shared__ __align__(16) _Float16 sH[2][16][SK];   // 4.6 KB h staging (f16)
    __shared__ int sInst[BB * T_STEPS];                // 4 KB

    const int tid  = (int)threadIdx.x;
    const int w    = tid >> 6;          // wave 0..7; also this wave's x-staging row
    const int l    = tid & 63;
    const int lrow = l & 15;            // A-row (m) / packed-n for B & C/D
    const int lk   = l >> 4;            // k-block; C/D rows are lk*4 + 0..3
    const bool losd = (lrow < 8);       // low gate-half of the packed tile
    const int col   = w * 8 + (lrow & 7);  // h-column of this lane's site
    const int rstar = losd ? 0 : 1;     // row-slot this lane owns
    const int mrow  = lk * 4 + rstar;   // LDS/M-row of the site
    const int br    = lk * 2 + rstar;   // batch row of the site
    const int b0    = (int)blockIdx.x * BB;

    const float L2E     = 1.4426950408889634f;
    const float TWO_L2E = 2.8853900817779268f;

    // stage this block's instruction indices (8 rows x 128 steps)
    for (int i = tid; i < BB * T_STEPS; i += NTHREADS)
        sInst[i] = inst[b0 * T_STEPS + i];

    // zero all staging once: h0 = 0 AND the 8 permanently-garbage M-rows
    for (int i = tid; i < 2 * 16 * SK; i += NTHREADS) {
        ((_Float16*)sX)[i] = (_Float16)0.0f;
        ((_Float16*)sH)[i] = (_Float16)0.0f;
    }
    __syncthreads();

    // weight B-fragments (f16, exp2-prescaled): tile q -> gate q*2 + (lrow>>3)
    // kf 0,1 -> W_ih k 0..63 ; kf 2,3 -> W_hh k 0..63
    half8 wf[2][4];
    float bias[2];
#pragma unroll
    for (int q = 0; q < 2; ++q) {
        const int gate = q * 2 + (lrow >> 3);
        const float ws = (gate == 2) ? TWO_L2E : L2E;  // g feeds tanh(2x form)
        const int gcol = gate * 64 + col;              // W output row 0..255
        bias[q] = (bih[gcol] + bhh[gcol]) * ws;
#pragma unroll
        for (int kf = 0; kf < 4; ++kf) {
            const float* src = (kf < 2 ? Wih : Whh) + (long)gcol * H_DIM + (kf & 1) * 32 + lk * 8;
            half8 v;
#pragma unroll
            for (int jj = 0; jj < 8; ++jj) v[jj] = (_Float16)(src[jj] * ws);
            wf[q][kf] = v;
        }
    }

    // x staging: wave w owns batch row w (M-row xmw), lane l owns feature l
    const int xmw = (w >> 1) * 4 + (w & 1);
    {   // x(0) straight to LDS
        const int idx = sInst[w * T_STEPS + 0];
        sX[0][xmw][l] = (_Float16)embed[(long)idx * H_DIM + l];
    }

    // register x-buffer (static indices only): entry (tt-1)&7 holds x(tt)
    float xbuf[XBATCH];
#pragma unroll
    for (int j = 0; j < XBATCH; ++j) {
        const int idx = sInst[w * T_STEPS + 1 + j];
        xbuf[j] = embed[(long)idx * H_DIM + l];
    }
    __syncthreads();

    float creg = 0.f, hreg = 0.f;   // this lane's single site (br, col)

    for (int tb = 0; tb < T_STEPS; tb += XBATCH) {
#pragma unroll
        for (int j = 0; j < XBATCH; ++j) {
            const int t   = tb + j;
            const int buf = j & 1;          // tb multiple of 8 -> static parity
            const int ob  = buf ^ 1;
            const bool pf = (t + 1 < T_STEPS);

            const float xcur = xbuf[j];     // x for step t+1 (loaded >=1 step ago)

            // refill burst once per XBATCH steps: x(t+2 .. t+9)
            if (j == XBATCH - 1 && pf) {
#pragma unroll
                for (int jj = 0; jj < XBATCH; ++jj) {
                    const int tt = t + 2 + jj;
                    if (tt < T_STEPS) {
                        const int idx = sInst[w * T_STEPS + tt];
                        xbuf[jj] = embed[(long)idx * H_DIM + l];
                    }
                }
            }

            // A-fragments (f16): lane (m=lrow, lk) reads 16B contiguous
            half8 a0 = *reinterpret_cast<const half8*>(&sX[buf][lrow][lk * 8]);
            half8 a1 = *reinterpret_cast<const half8*>(&sX[buf][lrow][32 + lk * 8]);
            half8 a2 = *reinterpret_cast<const half8*>(&sH[buf][lrow][lk * 8]);
            half8 a3 = *reinterpret_cast<const half8*>(&sH[buf][lrow][32 + lk * 8]);

            // 2 packed gate-pair tiles, two independent 4-deep MFMA chains
            f32x4 acc[2];
#pragma unroll
            for (int q = 0; q < 2; ++q) {
                f32x4 a = {bias[q], bias[q], bias[q], bias[q]};
                a = __builtin_amdgcn_mfma_f32_16x16x32_f16(a0, wf[q][0], a, 0, 0, 0);
                a = __builtin_amdgcn_mfma_f32_16x16x32_f16(a1, wf[q][1], a, 0, 0, 0);
                a = __builtin_amdgcn_mfma_f32_16x16x32_f16(a2, wf[q][2], a, 0, 0, 0);
                a = __builtin_amdgcn_mfma_f32_16x16x32_f16(a3, wf[q][3], a, 0, 0, 0);
                acc[q] = a;
            }

            // site-splitting exchange: losd owns slot 0, hi owns slot 1.
            // losd sends acc[1] (partner's i/g at its row), hi sends acc[0]
            // (partner's f/o at its row); one DPP per tile.
            const float recv0 = xor8_dpp(losd ? acc[0][1] : acc[0][0]);
            const float recv1 = xor8_dpp(losd ? acc[1][1] : acc[1][0]);
            const float vi = losd ? acc[0][0] : recv0;
            const float vf = losd ? recv0     : acc[0][1];
            const float vg = losd ? acc[1][0] : recv1;
            const float vo = losd ? recv1     : acc[1][1];

            // single-site cell update (gate order i,f,g,o), exp2 domain
            const float iv = sigmoid2(vi);
            const float fv = sigmoid2(vf);
            const float gv = tanh2(vg);
            const float ov = sigmoid2(vo);
            const float cs = fmaf(fv, creg, iv * (gv * TWO_L2E));  // scaled-c domain
            creg = cs;
            hreg = ov * tanh2(cs);

            if (pf) {
                sH[ob][mrow][col] = (_Float16)hreg;    // publish h (f16, RNE)
                sX[ob][xmw][l]    = (_Float16)xcur;    // publish prefetched x
            }
            __syncthreads();   // sX/sH[ob] visible before next step
        }
    }

    // final h (f32) -> out[B][H]; one element per lane
    out[(long)(b0 + br) * H_DIM + col] = hreg;
}

extern "C" void kernel_launch(void* const* d_in, const int* in_sizes, int n_in,
                              void* d_out, int out_size, void* d_ws, size_t ws_size,
                              hipStream_t stream) {
    const int*   inst  = (const int*)  d_in[0];
    const float* embed = (const float*)d_in[1];
    const float* Wih   = (const float*)d_in[2];
    const float* Whh   = (const float*)d_in[3];
    const float* bih   = (const float*)d_in[4];
    const float* bhh   = (const float*)d_in[5];
    float* out = (float*)d_out;

    lstm_fused<<<B_TOT / BB, NTHREADS, 0, stream>>>(inst, embed, Wih, Whh, bih, bhh, out);
}